// Round 3
// baseline (277.251 us; speedup 1.0000x reference)
//
#include <hip/hip_runtime.h>

// GaborLayer: out[p][o] = sin(x[p]·W[o] + b[o]) * exp(-0.5*gamma[o]*||x[p]-mu[o]||^2)
// P = 262144 points, OUT = 256, IN = 3. Output = 256 MiB fp32 -> write-BW bound.
//
// R4: write-PATTERN experiment. R1-R3 showed the kernel is inelastic to store
// type (NT vs plain), VALU count (-25%), and occupancy (4->8 waves/SIMD):
// ~105 us vs the 43 us write roofline. Issue-side is exonerated; the remaining
// structural difference vs the harness's 6.5 TB/s fill kernel is SPATIAL:
//   - old: each wave owned a contiguous 32 KiB chunk -> instantaneous write
//     footprint = 8192 separate 1 KiB islands spaced 32 KiB apart across the
//     whole 256 MiB (HBM row/bank thrash, unordered L2 evictions).
//   - new: grid-stride interleave. Wave w writes points {2w, 2w+1, 2w+16384,...}
//     -> consecutive waves write ADJACENT 1 KiB rows; the chip-wide footprint
//     is one dense ~16 MiB window marching forward, exactly like the fill.
// Kept: 8 waves/SIMD, plain dwordx4 stores, constants pre-folded into v_sin
// (revolutions) / v_exp (log2) domain, 1-iter-ahead wave-uniform s_load x.

#define OUT_F 256

typedef float v4f __attribute__((ext_vector_type(4)));

__global__ __launch_bounds__(256, 8) void gabor_kernel(
    const float* __restrict__ x,      // (P, 3)
    const float* __restrict__ W,      // (256, 3)
    const float* __restrict__ b,      // (256,)
    const float* __restrict__ mu,     // (256, 3)
    const float* __restrict__ gamma,  // (256,)
    float* __restrict__ out,          // (P, 256)
    int P)
{
    const int lane        = threadIdx.x & 63;
    const int waveInBlock = threadIdx.x >> 6;
    const int wavesPerBlk = blockDim.x >> 6;
    const int wavesTotal  = gridDim.x * wavesPerBlk;
    // Force wave-uniformity so x addressing is scalar (s_load, lgkmcnt).
    const int waveId = __builtin_amdgcn_readfirstlane(blockIdx.x * wavesPerBlk + waveInBlock);

    const int o = lane << 2;  // 4 consecutive out-features per lane

    constexpr float INV_2PI = 0.15915493667125702f;  // 1/(2*pi)
    constexpr float LOG2E   = 1.4426950408889634f;   // log2(e)

    // Per-feature constants, pre-folded (36 VGPRs, live whole kernel):
    //   lin_rev = wr·x + brv            (revolutions; feeds v_sin directly)
    //   ea      = aj*||x||^2 + n·x + dj (log2 units; feeds v_exp directly)
    float wr0[4], wr1[4], wr2[4], brv[4];
    float n0[4], n1[4], n2[4], dj[4], aj[4];
#pragma unroll
    for (int j = 0; j < 4; ++j) {
        const int oj = o + j;
        const float g2  = -0.5f * LOG2E * gamma[oj];
        const float m0v = mu[oj * 3 + 0];
        const float m1v = mu[oj * 3 + 1];
        const float m2v = mu[oj * 3 + 2];
        wr0[j] = W[oj * 3 + 0] * INV_2PI;
        wr1[j] = W[oj * 3 + 1] * INV_2PI;
        wr2[j] = W[oj * 3 + 2] * INV_2PI;
        brv[j] = b[oj] * INV_2PI;
        aj[j]  = g2;
        n0[j]  = -2.0f * g2 * m0v;
        n1[j]  = -2.0f * g2 * m1v;
        n2[j]  = -2.0f * g2 * m2v;
        dj[j]  = g2 * (m0v * m0v + m1v * m1v + m2v * m2v);
    }

    // Grid-stride interleave: 2 adjacent points per wave per step, consecutive
    // waves cover consecutive point-pairs (dense chip-wide write window).
    const int step = wavesTotal * 2;   // global points consumed per step
    int p = waveId * 2;

    if (p + 1 < P) {
        // Prologue: 6 wave-uniform scalar loads (this step's 2 points).
        float xv[6];
        {
            const float* xp = x + (size_t)p * 3;
#pragma unroll
            for (int i = 0; i < 6; ++i) xv[i] = xp[i];
        }

        while (p + 1 < P) {
            const int pn = p + step;
            // Prefetch next step's x while this one computes (clamped in-bounds).
            const int pf = (pn + 1 < P) ? pn : (P - 2);
            float xn[6];
            {
                const float* xq = x + (size_t)pf * 3;
#pragma unroll
                for (int i = 0; i < 6; ++i) xn[i] = xq[i];
            }

            float* orow = out + (size_t)p * OUT_F + o;
#pragma unroll
            for (int q = 0; q < 2; ++q) {
                const float x0 = xv[q * 3 + 0];
                const float x1 = xv[q * 3 + 1];
                const float x2 = xv[q * 3 + 2];
                const float xs = x0 * x0 + x1 * x1 + x2 * x2;
                v4f r;
#pragma unroll
                for (int j = 0; j < 4; ++j) {
                    const float lin = fmaf(wr0[j], x0, fmaf(wr1[j], x1, fmaf(wr2[j], x2, brv[j])));
                    const float t   = fmaf(n0[j], x0, fmaf(n1[j], x1, fmaf(n2[j], x2, dj[j])));
                    const float ea  = fmaf(aj[j], xs, t);
                    r[j] = __builtin_amdgcn_sinf(lin) * __builtin_amdgcn_exp2f(ea);
                }
                // Plain coalesced store: 64 lanes x 16B = one contiguous 1 KiB row;
                // waves w, w+1 write adjacent rows simultaneously.
                *reinterpret_cast<v4f*>(orow + (size_t)q * OUT_F) = r;
            }

            p = pn;
#pragma unroll
            for (int i = 0; i < 6; ++i) xv[i] = xn[i];
        }
    }

    // Tail for odd P (not hit at P = 262144; kept for safety).
    if (p < P) {
        const float x0 = x[p * 3 + 0];
        const float x1 = x[p * 3 + 1];
        const float x2 = x[p * 3 + 2];
        const float xs = x0 * x0 + x1 * x1 + x2 * x2;
        v4f r;
#pragma unroll
        for (int j = 0; j < 4; ++j) {
            const float lin = fmaf(wr0[j], x0, fmaf(wr1[j], x1, fmaf(wr2[j], x2, brv[j])));
            const float t   = fmaf(n0[j], x0, fmaf(n1[j], x1, fmaf(n2[j], x2, dj[j])));
            const float ea  = fmaf(aj[j], xs, t);
            r[j] = __builtin_amdgcn_sinf(lin) * __builtin_amdgcn_exp2f(ea);
        }
        *reinterpret_cast<v4f*>(out + (size_t)p * OUT_F + o) = r;
    }
}

extern "C" void kernel_launch(void* const* d_in, const int* in_sizes, int n_in,
                              void* d_out, int out_size, void* d_ws, size_t ws_size,
                              hipStream_t stream) {
    const float* x     = (const float*)d_in[0];
    const float* W     = (const float*)d_in[1];
    const float* b     = (const float*)d_in[2];
    const float* mu    = (const float*)d_in[3];
    const float* gamma = (const float*)d_in[4];
    float* out = (float*)d_out;

    const int P = in_sizes[0] / 3;  // B*N points

    // 2048 blocks x 4 waves = 8192 waves, all resident (256 CU x 4 SIMD x 8).
    // Grid-stride by 16384 points; 16 steps of 2 adjacent points per wave.
    gabor_kernel<<<2048, 256, 0, stream>>>(x, W, b, mu, gamma, out, P);
}